// Round 9
// baseline (180.019 us; speedup 1.0000x reference)
//
#include <hip/hip_runtime.h>

// ---------------------------------------------------------------------------
// GPT2 attention mixer: qkv GEMM -> causal flash attention -> proj GEMM
// B=2, S=2048, E=1024, H=16, HD=64.  All matmuls in bf16 MFMA 16x16x32.
// ---------------------------------------------------------------------------

typedef __bf16 bf16;
typedef __bf16 bf16x4 __attribute__((ext_vector_type(4)));
typedef __bf16 bf16x8 __attribute__((ext_vector_type(8)));
typedef float f32x4 __attribute__((ext_vector_type(4)));

#define GLOBAL_AS(p) ((const __attribute__((address_space(1))) void*)(p))
#define LDS_AS(p) ((__attribute__((address_space(3))) void*)(p))

__device__ __forceinline__ void g2l16(const void* g, void* l) {
  // async global->LDS, 16B per lane; LDS dest = wave-uniform base + lane*16
  __builtin_amdgcn_global_load_lds(GLOBAL_AS(g), LDS_AS(l), 16, 0, 0);
}

// Q is pre-scaled by 1/sqrt(64) * log2(e) in the QKV-GEMM epilogue, so
// scores come out of the QK^T MFMA already in the log2 domain.
#define QSCL 0.18033688f

// ---------------- fused prep: cast x + transpose both weights --------------
__global__ __launch_bounds__(256) void prep_kernel(
    const float* __restrict__ x, const float* __restrict__ wq,
    const float* __restrict__ wp, bf16* __restrict__ Xbf,
    bf16* __restrict__ Wqt, bf16* __restrict__ Wpt) {
  __shared__ float tile[32][33];
  const int t = threadIdx.x;
  const int b = blockIdx.x;
  if (b < 4096) {  // cast x -> bf16, 4 elems/thread
    const int i = (b * 256 + t) * 4;
    const float4 v = *(const float4*)(x + i);
    bf16x4 o;
    o.x = (bf16)v.x; o.y = (bf16)v.y; o.z = (bf16)v.z; o.w = (bf16)v.w;
    *(bf16x4*)(Xbf + i) = o;
    return;
  }
  const float* W; bf16* Wt; int C, bx, by;
  if (b < 7168) {  // w_qkv [1024,3072] -> Wqt [3072,1024]
    const int b2 = b - 4096;
    W = wq; Wt = Wqt; C = 3072; bx = b2 % 96; by = b2 / 96;
  } else {         // w_proj [1024,1024] -> Wpt [1024,1024]
    const int b3 = b - 7168;
    W = wp; Wt = Wpt; C = 1024; bx = b3 & 31; by = b3 >> 5;
  }
  const int c0 = bx * 32, r0 = by * 32;
  const int tx = t & 31, ty = t >> 5;  // 32 x 8
#pragma unroll
  for (int i = ty; i < 32; i += 8) tile[i][tx] = W[(r0 + i) * C + c0 + tx];
  __syncthreads();
#pragma unroll
  for (int i = ty; i < 32; i += 8)
    Wt[(c0 + i) * 1024 + r0 + tx] = (bf16)tile[tx][i];
}

// ---------------- GEMM1: QKV = X * Wqt^T + bias ----------------------------
// 128x128 tile, BK=32, 256 threads (4 waves, 2x2), wave = 64x64 = 4x4 MFMA.
// Q (scaled) / K scatter to [b,h,s,d].  V blocks (n0>=2048, block-uniform)
// transpose their C-tile through a padded LDS buffer (unioned with the
// staging buffers) and write V^T [b,h,d,s] as contiguous 16B chunks --
// 65K coalesced store transactions instead of 524K scattered 8B ones.
__global__ __launch_bounds__(256) void gemm_qkv_kernel(
    const bf16* __restrict__ A, const bf16* __restrict__ Bt,
    const float* __restrict__ bias, bf16* __restrict__ Qo,
    bf16* __restrict__ Ko, bf16* __restrict__ Vto) {
  constexpr int K = 1024;
  __shared__ bf16 smem[128 * 136];  // union: staging (8192) | V^T tile
  bf16* As = smem;                  // [128][32]
  bf16* Bs = smem + 4096;           // [128][32]
  const int t = threadIdx.x;
  const int m0 = blockIdx.x * 128;
  const int n0 = blockIdx.y * 128;
  const int wave = t >> 6, lane = t & 63;
  const int wr = (wave >> 1) * 64, wc = (wave & 1) * 64;
  const int lr = lane & 15, lg = lane >> 4;
  f32x4 acc[4][4] = {};
  const bf16* ag = A + (m0 + (t >> 2)) * K + (t & 3) * 8;
  const bf16* bg = Bt + (n0 + (t >> 2)) * K + (t & 3) * 8;
  for (int k0 = 0; k0 < K; k0 += 32) {
    __syncthreads();
    g2l16(ag, &As[t * 8]);
    g2l16(ag + 64 * K, &As[2048 + t * 8]);
    g2l16(bg, &Bs[t * 8]);
    g2l16(bg + 64 * K, &Bs[2048 + t * 8]);
    ag += 32; bg += 32;
    __syncthreads();
    bf16x8 af[4], bfr[4];
#pragma unroll
    for (int i = 0; i < 4; i++)
      af[i] = *(const bf16x8*)&As[(wr + i * 16 + lr) * 32 + lg * 8];
#pragma unroll
    for (int j = 0; j < 4; j++)
      bfr[j] = *(const bf16x8*)&Bs[(wc + j * 16 + lr) * 32 + lg * 8];
#pragma unroll
    for (int i = 0; i < 4; i++)
#pragma unroll
      for (int j = 0; j < 4; j++)
        acc[i][j] = __builtin_amdgcn_mfma_f32_16x16x32_bf16(af[i], bfr[j],
                                                            acc[i][j], 0, 0, 0);
  }
  // epilogue: C/D layout col = lane&15, row = (lane>>4)*4 + reg
  if (n0 >= 2048) {  // ---- V: LDS transpose, coalesced V^T store ----
    __syncthreads();  // staging reads done before smem reuse
#pragma unroll
    for (int i = 0; i < 4; i++) {
#pragma unroll
      for (int j = 0; j < 4; j++) {
        const int nl = wc + j * 16 + lr;        // n_local = head*64+d index
        const int ml = wr + i * 16 + lg * 4;    // m_local = s index
        const float bv = bias[n0 + nl];
        bf16x4 vv;
#pragma unroll
        for (int r = 0; r < 4; r++) vv[r] = (bf16)(acc[i][j][r] + bv);
        *(bf16x4*)&smem[nl * 136 + ml] = vv;    // 136 pad: 2-way banks (free)
      }
    }
    __syncthreads();
    const int e0 = n0 & 1023;      // n0-2048
    const int b = m0 >> 11, s0 = m0 & 2047;  // block never straddles b
#pragma unroll
    for (int rep = 0; rep < 8; rep++) {
      const int u = rep * 256 + t;      // 2048 chunks = 128 rows x 16
      const int row = u >> 4, seg = u & 15;
      const bf16x8 vv = *(const bf16x8*)&smem[row * 136 + seg * 8];
      const int e = e0 + row, h = e >> 6, d = e & 63;
      *(bf16x8*)(Vto + ((size_t)((b * 16 + h) * 64 + d)) * 2048 + s0 +
                 seg * 8) = vv;
    }
  } else {  // ---- Q (scaled) / K -> [b,h,s,d] ----
#pragma unroll
    for (int i = 0; i < 4; i++) {
#pragma unroll
      for (int j = 0; j < 4; j++) {
        const int n = n0 + wc + j * 16 + lr;
        const float bv = bias[n];
        const int e = n & 1023, h = e >> 6, d = e & 63;
        const bool isq = (n < 1024);
        bf16* dst = isq ? Qo : Ko;
#pragma unroll
        for (int r = 0; r < 4; r++) {
          const int m = m0 + wr + i * 16 + lg * 4 + r;
          const int b = m >> 11, s = m & 2047;
          const float v = acc[i][j][r] + bv;
          dst[((b * 16 + h) * 2048 + s) * 64 + d] = (bf16)(isq ? v * QSCL : v);
        }
      }
    }
  }
}

// ---------------- GEMM2: out = Obf * Wpt^T + bias (f32 out) ----------------
// 64x64 tile, BK=32, 256 threads (4 waves 2x2), wave = 32x32 = 2x2 MFMA.
// Grid 64x16 = 1024 blocks -> 4 blocks/CU; cross-block wave overlap hides
// the per-iter staging drains (m114).
__global__ __launch_bounds__(256) void gemm_proj_kernel(
    const bf16* __restrict__ A, const bf16* __restrict__ Bt,
    const float* __restrict__ bias, float* __restrict__ Cf) {
  constexpr int K = 1024, N = 1024;
  __shared__ bf16 As[64 * 32];
  __shared__ bf16 Bs[64 * 32];
  const int t = threadIdx.x;
  const int m0 = blockIdx.x * 64;
  const int n0 = blockIdx.y * 64;
  const int wave = t >> 6, lane = t & 63;
  const int wr = (wave >> 1) * 32, wc = (wave & 1) * 32;
  const int lr = lane & 15, lg = lane >> 4;
  f32x4 acc[2][2] = {};
  const bf16* ag = A + (m0 + (t >> 2)) * K + (t & 3) * 8;
  const bf16* bg = Bt + (n0 + (t >> 2)) * K + (t & 3) * 8;
  for (int k0 = 0; k0 < K; k0 += 32) {
    __syncthreads();
    g2l16(ag, &As[t * 8]);
    g2l16(bg, &Bs[t * 8]);
    ag += 32; bg += 32;
    __syncthreads();
    bf16x8 af[2], bfr[2];
#pragma unroll
    for (int i = 0; i < 2; i++)
      af[i] = *(const bf16x8*)&As[(wr + i * 16 + lr) * 32 + lg * 8];
#pragma unroll
    for (int j = 0; j < 2; j++)
      bfr[j] = *(const bf16x8*)&Bs[(wc + j * 16 + lr) * 32 + lg * 8];
#pragma unroll
    for (int i = 0; i < 2; i++)
#pragma unroll
      for (int j = 0; j < 2; j++)
        acc[i][j] = __builtin_amdgcn_mfma_f32_16x16x32_bf16(af[i], bfr[j],
                                                            acc[i][j], 0, 0, 0);
  }
#pragma unroll
  for (int i = 0; i < 2; i++) {
#pragma unroll
    for (int j = 0; j < 2; j++) {
      const int n = n0 + wc + j * 16 + lr;
      const float bv = bias[n];
#pragma unroll
      for (int r = 0; r < 4; r++) {
        const int m = m0 + wr + i * 16 + lg * 4 + r;
        Cf[m * N + n] = acc[i][j][r] + bv;
      }
    }
  }
}

// ---------------- causal flash attention, v7: single-buffer ----------------
// Fixed-max softmax (proven r7), full diagonal masking, single-buffered K/V
// (25.6 KB LDS), XCD-pinned bh, heavy strips first, grid 1024 = 4 blocks/CU.
__device__ __forceinline__ void stage_kv(const bf16* __restrict__ Kg,
                                         const bf16* __restrict__ Vg, int kb,
                                         bf16* ks, bf16* vs, int t) {
  // XOR-swizzle on 16B chunks: global chunk (r, c^(r&7)) -> LDS slot (r, c)
  int u = t, r = u >> 3, c = (u & 7) ^ (r & 7);
  g2l16(Kg + (kb + r) * 64 + c * 8, ks + u * 8);
  g2l16(Vg + r * 2048 + kb + c * 8, vs + u * 8);
  u = 256 + t; r = u >> 3; c = (u & 7) ^ (r & 7);
  g2l16(Kg + (kb + r) * 64 + c * 8, ks + u * 8);
  g2l16(Vg + r * 2048 + kb + c * 8, vs + u * 8);
}

__global__ __launch_bounds__(256, 4) void attn_kernel(
    const bf16* __restrict__ Qb, const bf16* __restrict__ Kb,
    const bf16* __restrict__ Vt, bf16* __restrict__ Obf) {
  __shared__ bf16 Ks[64 * 64];
  __shared__ bf16 Vs[64 * 64];
  __shared__ bf16 Ps[4][16 * 72];
  const int t = threadIdx.x;
  const int w = t >> 6, lane = t & 63;
  const int lr = lane & 15, lg = lane >> 4;
  const int bx = blockIdx.x;
  const int xcd = bx & 7, idx = bx >> 3;   // 1024 blocks = 8 XCD x 128
  const int bh = (idx & 3) * 8 + xcd;      // head pinned to one XCD
  const int strip = 31 - (idx >> 2);       // heavy strips dispatch first
  const int qb = strip * 64 + w * 16;      // wave's 16 q-rows
  const bf16* Qg = Qb + (size_t)bh * 2048 * 64;
  const bf16* Kg = Kb + (size_t)bh * 2048 * 64;
  const bf16* Vg = Vt + (size_t)bh * 64 * 2048;
  // persistent Q B-fragments (pre-scaled into log2 domain)
  bf16x8 bq[2];
#pragma unroll
  for (int h = 0; h < 2; h++)
    bq[h] = *(const bf16x8*)(Qg + (qb + lr) * 64 + h * 32 + lg * 8);
  f32x4 oacc[4] = {};
  float lsum = 0.f;
  bf16* ps = &Ps[w][0];
  const int T = strip + 1;
  for (int ti = 0; ti < T; ++ti) {
    __syncthreads();  // all waves done reading the previous tile
    stage_kv(Kg, Vg, ti * 64, Ks, Vs, t);
    __syncthreads();  // staging visible (drains the g2l16 loads)
    const int kb = ti * 64;
    // fragments from swizzled LDS (row&7 == lr&7 since rows step by 16)
    bf16x8 ak[4][2], av[4][2];
#pragma unroll
    for (int j = 0; j < 4; j++) {
      const int row = j * 16 + lr;
#pragma unroll
      for (int h = 0; h < 2; h++)
        ak[j][h] =
            *(const bf16x8*)(Ks + (row * 8 + ((h * 4 + lg) ^ (row & 7))) * 8);
    }
#pragma unroll
    for (int dt = 0; dt < 4; dt++) {
      const int row = dt * 16 + lr;
#pragma unroll
      for (int h = 0; h < 2; h++)
        av[dt][h] =
            *(const bf16x8*)(Vs + (row * 8 + ((h * 4 + lg) ^ (row & 7))) * 8);
    }
    // S^T[k][q]: C-layout col=q=lr, row=k_local=lg*4+r
    f32x4 sacc[4];
#pragma unroll
    for (int j = 0; j < 4; j++) {
      f32x4 s = {};
      s = __builtin_amdgcn_mfma_f32_16x16x32_bf16(ak[j][0], bq[0], s, 0, 0, 0);
      s = __builtin_amdgcn_mfma_f32_16x16x32_bf16(ak[j][1], bq[1], s, 0, 0, 0);
      sacc[j] = s;
    }
    // fixed-max softmax: p = exp2(s), per-lane partial l
    const bool diag = (kb + 63 > qb);  // wave-uniform: last tile only
    bf16x4 pk[4];
#pragma unroll
    for (int j = 0; j < 4; j++)
#pragma unroll
      for (int r = 0; r < 4; r++) {
        float v = sacc[j][r];
        if (diag && (kb + j * 16 + lg * 4 + r > qb + lr)) v = -1e30f;
        const float e = __builtin_amdgcn_exp2f(v);
        lsum += e;
        pk[j][r] = (bf16)e;
      }
    // P[q][k] -> per-wave LDS -> B-frag; wave-local fence, no block barrier
    asm volatile("" ::: "memory");
#pragma unroll
    for (int j = 0; j < 4; j++)
      *(bf16x4*)(ps + lr * 72 + j * 16 + lg * 4) = pk[j];
    asm volatile("s_waitcnt lgkmcnt(0)" ::: "memory");
    bf16x8 bp[2];
#pragma unroll
    for (int h = 0; h < 2; h++)
      bp[h] = *(const bf16x8*)(ps + lr * 72 + h * 32 + lg * 8);
    // O^T[d][q] += V^T P^T (no rescale: fixed max)
#pragma unroll
    for (int dt = 0; dt < 4; dt++) {
      f32x4 o = oacc[dt];
      o = __builtin_amdgcn_mfma_f32_16x16x32_bf16(av[dt][0], bp[0], o, 0, 0, 0);
      o = __builtin_amdgcn_mfma_f32_16x16x32_bf16(av[dt][1], bp[1], o, 0, 0, 0);
      oacc[dt] = o;
    }
  }
  // epilogue: single cross-lane l reduction, then O/l -> Obf[b, s=q, h*64+d]
  lsum += __shfl_xor(lsum, 16, 64);
  lsum += __shfl_xor(lsum, 32, 64);
  const float inv = 1.0f / lsum;
  const int b = bh >> 4, hh = bh & 15;
  const int q = qb + lr;
  bf16* orow = Obf + ((size_t)(b * 2048 + q)) * 1024 + hh * 64;
#pragma unroll
  for (int dt = 0; dt < 4; dt++) {
    bf16x4 ov;
#pragma unroll
    for (int r = 0; r < 4; r++) ov[r] = (bf16)(oacc[dt][r] * inv);
    *(bf16x4*)(orow + dt * 16 + lg * 4) = ov;
  }
}

// ---------------------------------------------------------------------------
extern "C" void kernel_launch(void* const* d_in, const int* in_sizes, int n_in,
                              void* d_out, int out_size, void* d_ws,
                              size_t ws_size, hipStream_t stream) {
  const float* x      = (const float*)d_in[0];  // [2,2048,1024]
  const float* w_qkv  = (const float*)d_in[1];  // [1024,3072]
  const float* b_qkv  = (const float*)d_in[2];  // [3072]
  const float* w_proj = (const float*)d_in[3];  // [1024,1024]
  const float* b_proj = (const float*)d_in[4];  // [1024]
  float* out = (float*)d_out;                   // [2,2048,1024] f32

  char* w = (char*)d_ws;
  bf16* Xbf = (bf16*)w;  w += 4096 * 1024 * 2;        // 8 MiB
  bf16* Wqt = (bf16*)w;  w += 3072 * 1024 * 2;        // 6 MiB  (w_qkv^T)
  bf16* Wpt = (bf16*)w;  w += 1024 * 1024 * 2;        // 2 MiB  (w_proj^T)
  bf16* Qb  = (bf16*)w;  w += 2 * 16 * 2048 * 64 * 2; // 8 MiB [b,h,s,d]
  bf16* Kb  = (bf16*)w;  w += 2 * 16 * 2048 * 64 * 2; // 8 MiB [b,h,s,d]
  bf16* Vt  = (bf16*)w;  w += 2 * 16 * 64 * 2048 * 2; // 8 MiB [b,h,d,s]
  bf16* Obf = (bf16*)w;  w += 4096 * 1024 * 2;        // 8 MiB [b,s,h*d]

  prep_kernel<<<8192, 256, 0, stream>>>(x, w_qkv, w_proj, Xbf, Wqt, Wpt);
  gemm_qkv_kernel<<<dim3(32, 24), 256, 0, stream>>>(
      Xbf, Wqt, b_qkv, Qb, Kb, Vt);
  attn_kernel<<<1024, 256, 0, stream>>>(Qb, Kb, Vt, Obf);
  gemm_proj_kernel<<<dim3(64, 16), 256, 0, stream>>>(Obf, Wpt, b_proj, out);
}

// Round 10
// 178.195 us; speedup vs baseline: 1.0102x; 1.0102x over previous
//
#include <hip/hip_runtime.h>

// ---------------------------------------------------------------------------
// GPT2 attention mixer: qkv GEMM -> causal flash attention -> proj GEMM
// B=2, S=2048, E=1024, H=16, HD=64.  All matmuls in bf16 MFMA 16x16x32.
// ---------------------------------------------------------------------------

typedef __bf16 bf16;
typedef __bf16 bf16x4 __attribute__((ext_vector_type(4)));
typedef __bf16 bf16x8 __attribute__((ext_vector_type(8)));
typedef float f32x4 __attribute__((ext_vector_type(4)));

#define GLOBAL_AS(p) ((const __attribute__((address_space(1))) void*)(p))
#define LDS_AS(p) ((__attribute__((address_space(3))) void*)(p))

__device__ __forceinline__ void g2l16(const void* g, void* l) {
  // async global->LDS, 16B per lane; LDS dest = wave-uniform base + lane*16
  __builtin_amdgcn_global_load_lds(GLOBAL_AS(g), LDS_AS(l), 16, 0, 0);
}

// Q is pre-scaled by 1/sqrt(64) * log2(e) in the QKV-GEMM epilogue, so
// scores come out of the QK^T MFMA already in the log2 domain.
#define QSCL 0.18033688f

// ---------------- fused prep: cast x + transpose both weights --------------
__global__ __launch_bounds__(256) void prep_kernel(
    const float* __restrict__ x, const float* __restrict__ wq,
    const float* __restrict__ wp, bf16* __restrict__ Xbf,
    bf16* __restrict__ Wqt, bf16* __restrict__ Wpt) {
  __shared__ float tile[32][33];
  const int t = threadIdx.x;
  const int b = blockIdx.x;
  if (b < 4096) {  // cast x -> bf16, 4 elems/thread
    const int i = (b * 256 + t) * 4;
    const float4 v = *(const float4*)(x + i);
    bf16x4 o;
    o.x = (bf16)v.x; o.y = (bf16)v.y; o.z = (bf16)v.z; o.w = (bf16)v.w;
    *(bf16x4*)(Xbf + i) = o;
    return;
  }
  const float* W; bf16* Wt; int C, bx, by;
  if (b < 7168) {  // w_qkv [1024,3072] -> Wqt [3072,1024]
    const int b2 = b - 4096;
    W = wq; Wt = Wqt; C = 3072; bx = b2 % 96; by = b2 / 96;
  } else {         // w_proj [1024,1024] -> Wpt [1024,1024]
    const int b3 = b - 7168;
    W = wp; Wt = Wpt; C = 1024; bx = b3 & 31; by = b3 >> 5;
  }
  const int c0 = bx * 32, r0 = by * 32;
  const int tx = t & 31, ty = t >> 5;  // 32 x 8
#pragma unroll
  for (int i = ty; i < 32; i += 8) tile[i][tx] = W[(r0 + i) * C + c0 + tx];
  __syncthreads();
#pragma unroll
  for (int i = ty; i < 32; i += 8)
    Wt[(c0 + i) * 1024 + r0 + tx] = (bf16)tile[tx][i];
}

// ---------------- GEMM1: QKV = X * Wqt^T + bias ----------------------------
// 128x128 tile, BK=64 (16 iters, 32 MFMA per barrier window), 256 threads,
// XOR-swizzled LDS staging (same proven pattern as attn's stage_kv) ->
// conflict-free ds_read_b128 fragments.  Epilogue: Q (scaled) / K scatter to
// [b,h,s,d]; V blocks (n0>=2048, block-uniform) write V^T [b,h,d,s] via
// bf16x4 (lane's 4 acc values = 4 consecutive s at fixed d).
__global__ __launch_bounds__(256) void gemm_qkv_kernel(
    const bf16* __restrict__ A, const bf16* __restrict__ Bt,
    const float* __restrict__ bias, bf16* __restrict__ Qo,
    bf16* __restrict__ Ko, bf16* __restrict__ Vto) {
  constexpr int K = 1024;
  __shared__ bf16 As[128 * 64];
  __shared__ bf16 Bs[128 * 64];
  const int t = threadIdx.x;
  const int m0 = blockIdx.x * 128;
  const int n0 = blockIdx.y * 128;
  const int wave = t >> 6, lane = t & 63;
  const int wr = (wave >> 1) * 64, wc = (wave & 1) * 64;
  const int lr = lane & 15, lg = lane >> 4;
  f32x4 acc[4][4] = {};
  for (int k0 = 0; k0 < K; k0 += 64) {
    __syncthreads();  // prev iteration done reading LDS
    // stage A,B 128x64 tiles: 1024 chunks each, XOR-swizzled
#pragma unroll
    for (int p = 0; p < 4; p++) {
      const int u = p * 256 + t;
      const int r = u >> 3, c = (u & 7) ^ (r & 7);
      g2l16(A + (m0 + r) * K + k0 + c * 8, &As[u * 8]);
      g2l16(Bt + (n0 + r) * K + k0 + c * 8, &Bs[u * 8]);
    }
    __syncthreads();  // staging visible (drains g2l16)
    bf16x8 af[4][2], bfr[4][2];
#pragma unroll
    for (int i = 0; i < 4; i++) {
      const int row = wr + i * 16 + lr;
#pragma unroll
      for (int kk = 0; kk < 2; kk++)
        af[i][kk] =
            *(const bf16x8*)&As[(row * 8 + ((kk * 4 + lg) ^ (row & 7))) * 8];
    }
#pragma unroll
    for (int j = 0; j < 4; j++) {
      const int row = wc + j * 16 + lr;
#pragma unroll
      for (int kk = 0; kk < 2; kk++)
        bfr[j][kk] =
            *(const bf16x8*)&Bs[(row * 8 + ((kk * 4 + lg) ^ (row & 7))) * 8];
    }
#pragma unroll
    for (int kk = 0; kk < 2; kk++)
#pragma unroll
      for (int i = 0; i < 4; i++)
#pragma unroll
        for (int j = 0; j < 4; j++)
          acc[i][j] = __builtin_amdgcn_mfma_f32_16x16x32_bf16(
              af[i][kk], bfr[j][kk], acc[i][j], 0, 0, 0);
  }
  // epilogue: C/D layout col = lane&15, row = (lane>>4)*4 + reg
#pragma unroll
  for (int i = 0; i < 4; i++) {
#pragma unroll
    for (int j = 0; j < 4; j++) {
      const int n = n0 + wc + j * 16 + lr;
      const float bv = bias[n];
      if (n0 >= 2048) {  // V -> Vt[b,h,d,s], vectorized along s
        const int e = n & 1023, h = e >> 6, d = e & 63;
        const int mb = m0 + wr + i * 16 + lg * 4;
        const int b = mb >> 11, s = mb & 2047;
        bf16x4 vv;
#pragma unroll
        for (int r = 0; r < 4; r++) vv[r] = (bf16)(acc[i][j][r] + bv);
        *(bf16x4*)(Vto + ((size_t)((b * 16 + h) * 64 + d)) * 2048 + s) = vv;
      } else {  // Q (scaled) / K -> [b,h,s,d]
        const int e = n & 1023, h = e >> 6, d = e & 63;
        const bool isq = (n < 1024);
        bf16* dst = isq ? Qo : Ko;
#pragma unroll
        for (int r = 0; r < 4; r++) {
          const int m = m0 + wr + i * 16 + lg * 4 + r;
          const int b = m >> 11, s = m & 2047;
          const float v = acc[i][j][r] + bv;
          dst[((b * 16 + h) * 2048 + s) * 64 + d] = (bf16)(isq ? v * QSCL : v);
        }
      }
    }
  }
}

// ---------------- GEMM2: out = Obf * Wpt^T + bias (f32 out) ----------------
// 64x64 tile, BK=64 (16 iters, 8 MFMA per window), 256 threads, XOR-swizzled
// staging.  Grid 64x16 = 1024 blocks -> 4 blocks/CU.
__global__ __launch_bounds__(256) void gemm_proj_kernel(
    const bf16* __restrict__ A, const bf16* __restrict__ Bt,
    const float* __restrict__ bias, float* __restrict__ Cf) {
  constexpr int K = 1024, N = 1024;
  __shared__ bf16 As[64 * 64];
  __shared__ bf16 Bs[64 * 64];
  const int t = threadIdx.x;
  const int m0 = blockIdx.x * 64;
  const int n0 = blockIdx.y * 64;
  const int wave = t >> 6, lane = t & 63;
  const int wr = (wave >> 1) * 32, wc = (wave & 1) * 32;
  const int lr = lane & 15, lg = lane >> 4;
  f32x4 acc[2][2] = {};
  for (int k0 = 0; k0 < K; k0 += 64) {
    __syncthreads();
#pragma unroll
    for (int p = 0; p < 2; p++) {
      const int u = p * 256 + t;
      const int r = u >> 3, c = (u & 7) ^ (r & 7);
      g2l16(A + (m0 + r) * K + k0 + c * 8, &As[u * 8]);
      g2l16(Bt + (n0 + r) * K + k0 + c * 8, &Bs[u * 8]);
    }
    __syncthreads();
    bf16x8 af[2][2], bfr[2][2];
#pragma unroll
    for (int i = 0; i < 2; i++) {
      const int row = wr + i * 16 + lr;
#pragma unroll
      for (int kk = 0; kk < 2; kk++)
        af[i][kk] =
            *(const bf16x8*)&As[(row * 8 + ((kk * 4 + lg) ^ (row & 7))) * 8];
    }
#pragma unroll
    for (int j = 0; j < 2; j++) {
      const int row = wc + j * 16 + lr;
#pragma unroll
      for (int kk = 0; kk < 2; kk++)
        bfr[j][kk] =
            *(const bf16x8*)&Bs[(row * 8 + ((kk * 4 + lg) ^ (row & 7))) * 8];
    }
#pragma unroll
    for (int kk = 0; kk < 2; kk++)
#pragma unroll
      for (int i = 0; i < 2; i++)
#pragma unroll
        for (int j = 0; j < 2; j++)
          acc[i][j] = __builtin_amdgcn_mfma_f32_16x16x32_bf16(
              af[i][kk], bfr[j][kk], acc[i][j], 0, 0, 0);
  }
#pragma unroll
  for (int i = 0; i < 2; i++) {
#pragma unroll
    for (int j = 0; j < 2; j++) {
      const int n = n0 + wc + j * 16 + lr;
      const float bv = bias[n];
#pragma unroll
      for (int r = 0; r < 4; r++) {
        const int m = m0 + wr + i * 16 + lg * 4 + r;
        Cf[m * N + n] = acc[i][j][r] + bv;
      }
    }
  }
}

// ---------------- causal flash attention, v7: single-buffer ----------------
// Fixed-max softmax (proven r7), full diagonal masking, single-buffered K/V
// (25.6 KB LDS), XCD-pinned bh, heavy strips first, grid 1024 = 4 blocks/CU.
__device__ __forceinline__ void stage_kv(const bf16* __restrict__ Kg,
                                         const bf16* __restrict__ Vg, int kb,
                                         bf16* ks, bf16* vs, int t) {
  // XOR-swizzle on 16B chunks: global chunk (r, c^(r&7)) -> LDS slot (r, c)
  int u = t, r = u >> 3, c = (u & 7) ^ (r & 7);
  g2l16(Kg + (kb + r) * 64 + c * 8, ks + u * 8);
  g2l16(Vg + r * 2048 + kb + c * 8, vs + u * 8);
  u = 256 + t; r = u >> 3; c = (u & 7) ^ (r & 7);
  g2l16(Kg + (kb + r) * 64 + c * 8, ks + u * 8);
  g2l16(Vg + r * 2048 + kb + c * 8, vs + u * 8);
}

__global__ __launch_bounds__(256, 4) void attn_kernel(
    const bf16* __restrict__ Qb, const bf16* __restrict__ Kb,
    const bf16* __restrict__ Vt, bf16* __restrict__ Obf) {
  __shared__ bf16 Ks[64 * 64];
  __shared__ bf16 Vs[64 * 64];
  __shared__ bf16 Ps[4][16 * 72];
  const int t = threadIdx.x;
  const int w = t >> 6, lane = t & 63;
  const int lr = lane & 15, lg = lane >> 4;
  const int bx = blockIdx.x;
  const int xcd = bx & 7, idx = bx >> 3;   // 1024 blocks = 8 XCD x 128
  const int bh = (idx & 3) * 8 + xcd;      // head pinned to one XCD
  const int strip = 31 - (idx >> 2);       // heavy strips dispatch first
  const int qb = strip * 64 + w * 16;      // wave's 16 q-rows
  const bf16* Qg = Qb + (size_t)bh * 2048 * 64;
  const bf16* Kg = Kb + (size_t)bh * 2048 * 64;
  const bf16* Vg = Vt + (size_t)bh * 64 * 2048;
  // persistent Q B-fragments (pre-scaled into log2 domain)
  bf16x8 bq[2];
#pragma unroll
  for (int h = 0; h < 2; h++)
    bq[h] = *(const bf16x8*)(Qg + (qb + lr) * 64 + h * 32 + lg * 8);
  f32x4 oacc[4] = {};
  float lsum = 0.f;
  bf16* ps = &Ps[w][0];
  const int T = strip + 1;
  for (int ti = 0; ti < T; ++ti) {
    __syncthreads();  // all waves done reading the previous tile
    stage_kv(Kg, Vg, ti * 64, Ks, Vs, t);
    __syncthreads();  // staging visible (drains the g2l16 loads)
    const int kb = ti * 64;
    // fragments from swizzled LDS (row&7 == lr&7 since rows step by 16)
    bf16x8 ak[4][2], av[4][2];
#pragma unroll
    for (int j = 0; j < 4; j++) {
      const int row = j * 16 + lr;
#pragma unroll
      for (int h = 0; h < 2; h++)
        ak[j][h] =
            *(const bf16x8*)(Ks + (row * 8 + ((h * 4 + lg) ^ (row & 7))) * 8);
    }
#pragma unroll
    for (int dt = 0; dt < 4; dt++) {
      const int row = dt * 16 + lr;
#pragma unroll
      for (int h = 0; h < 2; h++)
        av[dt][h] =
            *(const bf16x8*)(Vs + (row * 8 + ((h * 4 + lg) ^ (row & 7))) * 8);
    }
    // S^T[k][q]: C-layout col=q=lr, row=k_local=lg*4+r
    f32x4 sacc[4];
#pragma unroll
    for (int j = 0; j < 4; j++) {
      f32x4 s = {};
      s = __builtin_amdgcn_mfma_f32_16x16x32_bf16(ak[j][0], bq[0], s, 0, 0, 0);
      s = __builtin_amdgcn_mfma_f32_16x16x32_bf16(ak[j][1], bq[1], s, 0, 0, 0);
      sacc[j] = s;
    }
    // fixed-max softmax: p = exp2(s), per-lane partial l
    const bool diag = (kb + 63 > qb);  // wave-uniform: last tile only
    bf16x4 pk[4];
#pragma unroll
    for (int j = 0; j < 4; j++)
#pragma unroll
      for (int r = 0; r < 4; r++) {
        float v = sacc[j][r];
        if (diag && (kb + j * 16 + lg * 4 + r > qb + lr)) v = -1e30f;
        const float e = __builtin_amdgcn_exp2f(v);
        lsum += e;
        pk[j][r] = (bf16)e;
      }
    // P[q][k] -> per-wave LDS -> B-frag; wave-local fence, no block barrier
    asm volatile("" ::: "memory");
#pragma unroll
    for (int j = 0; j < 4; j++)
      *(bf16x4*)(ps + lr * 72 + j * 16 + lg * 4) = pk[j];
    asm volatile("s_waitcnt lgkmcnt(0)" ::: "memory");
    bf16x8 bp[2];
#pragma unroll
    for (int h = 0; h < 2; h++)
      bp[h] = *(const bf16x8*)(ps + lr * 72 + h * 32 + lg * 8);
    // O^T[d][q] += V^T P^T (no rescale: fixed max)
#pragma unroll
    for (int dt = 0; dt < 4; dt++) {
      f32x4 o = oacc[dt];
      o = __builtin_amdgcn_mfma_f32_16x16x32_bf16(av[dt][0], bp[0], o, 0, 0, 0);
      o = __builtin_amdgcn_mfma_f32_16x16x32_bf16(av[dt][1], bp[1], o, 0, 0, 0);
      oacc[dt] = o;
    }
  }
  // epilogue: single cross-lane l reduction, then O/l -> Obf[b, s=q, h*64+d]
  lsum += __shfl_xor(lsum, 16, 64);
  lsum += __shfl_xor(lsum, 32, 64);
  const float inv = 1.0f / lsum;
  const int b = bh >> 4, hh = bh & 15;
  const int q = qb + lr;
  bf16* orow = Obf + ((size_t)(b * 2048 + q)) * 1024 + hh * 64;
#pragma unroll
  for (int dt = 0; dt < 4; dt++) {
    bf16x4 ov;
#pragma unroll
    for (int r = 0; r < 4; r++) ov[r] = (bf16)(oacc[dt][r] * inv);
    *(bf16x4*)(orow + dt * 16 + lg * 4) = ov;
  }
}

// ---------------------------------------------------------------------------
extern "C" void kernel_launch(void* const* d_in, const int* in_sizes, int n_in,
                              void* d_out, int out_size, void* d_ws,
                              size_t ws_size, hipStream_t stream) {
  const float* x      = (const float*)d_in[0];  // [2,2048,1024]
  const float* w_qkv  = (const float*)d_in[1];  // [1024,3072]
  const float* b_qkv  = (const float*)d_in[2];  // [3072]
  const float* w_proj = (const float*)d_in[3];  // [1024,1024]
  const float* b_proj = (const float*)d_in[4];  // [1024]
  float* out = (float*)d_out;                   // [2,2048,1024] f32

  char* w = (char*)d_ws;
  bf16* Xbf = (bf16*)w;  w += 4096 * 1024 * 2;        // 8 MiB
  bf16* Wqt = (bf16*)w;  w += 3072 * 1024 * 2;        // 6 MiB  (w_qkv^T)
  bf16* Wpt = (bf16*)w;  w += 1024 * 1024 * 2;        // 2 MiB  (w_proj^T)
  bf16* Qb  = (bf16*)w;  w += 2 * 16 * 2048 * 64 * 2; // 8 MiB [b,h,s,d]
  bf16* Kb  = (bf16*)w;  w += 2 * 16 * 2048 * 64 * 2; // 8 MiB [b,h,s,d]
  bf16* Vt  = (bf16*)w;  w += 2 * 16 * 64 * 2048 * 2; // 8 MiB [b,h,d,s]
  bf16* Obf = (bf16*)w;  w += 4096 * 1024 * 2;        // 8 MiB [b,s,h*d]

  prep_kernel<<<8192, 256, 0, stream>>>(x, w_qkv, w_proj, Xbf, Wqt, Wpt);
  gemm_qkv_kernel<<<dim3(32, 24), 256, 0, stream>>>(
      Xbf, Wqt, b_qkv, Qb, Kb, Vt);
  attn_kernel<<<1024, 256, 0, stream>>>(Qb, Kb, Vt, Obf);
  gemm_proj_kernel<<<dim3(64, 16), 256, 0, stream>>>(Obf, Wpt, b_proj, out);
}